// Round 1
// baseline (274.514 us; speedup 1.0000x reference)
//
#include <hip/hip_runtime.h>
#include <hip/hip_bf16.h>

// Problem constants
#define BATCH 2
#define SEQ   2048
#define EMBD  1024
#define NHEAD 16
#define HDIM  64
#define N3    3072           // 3*EMBD
#define MTOT  4096           // BATCH*SEQ
#define KDIM  1024

typedef __attribute__((ext_vector_type(8))) short  short8;   // 8 x bf16 (4 VGPRs)
typedef __attribute__((ext_vector_type(4))) short  s16x4;
typedef __attribute__((ext_vector_type(4))) unsigned short u16x4;
typedef __attribute__((ext_vector_type(4))) float  f32x4;

__device__ __forceinline__ unsigned short f2bf(float f) {
    unsigned int u = __builtin_bit_cast(unsigned int, f);
    u += 0x7fffu + ((u >> 16) & 1u);          // RNE
    return (unsigned short)(u >> 16);
}

// ---------------------------------------------------------------- cast x -> bf16
__global__ __launch_bounds__(256) void cast_x_kernel(const float* __restrict__ x,
                                                     short* __restrict__ xb, int n4) {
    int i = blockIdx.x * 256 + threadIdx.x;
    if (i >= n4) return;
    float4 f = reinterpret_cast<const float4*>(x)[i];
    s16x4 o;
    o[0] = (short)f2bf(f.x); o[1] = (short)f2bf(f.y);
    o[2] = (short)f2bf(f.z); o[3] = (short)f2bf(f.w);
    reinterpret_cast<s16x4*>(xb)[i] = o;
}

// ------------------------------------------- cast + transpose w [K,N3] -> wt [N3,K]
__global__ __launch_bounds__(256) void cast_wt_kernel(const float* __restrict__ w,
                                                      short* __restrict__ wt) {
    __shared__ float tile[32][33];
    int n0 = blockIdx.x * 32;   // N3/32 = 96
    int k0 = blockIdx.y * 32;   // K/32  = 32
    int tx = threadIdx.x & 31;
    int ty = threadIdx.x >> 5;  // 0..7
#pragma unroll
    for (int i = 0; i < 4; ++i)
        tile[ty + i * 8][tx] = w[(size_t)(k0 + ty + i * 8) * N3 + n0 + tx];
    __syncthreads();
#pragma unroll
    for (int i = 0; i < 4; ++i)
        wt[(size_t)(n0 + ty + i * 8) * KDIM + k0 + tx] = (short)f2bf(tile[tx][ty + i * 8]);
}

// ---------------------------------------------------------------- QKV GEMM
// C[m,n] = sum_k xb[m,k] * wt[n,k];  M=4096, N=3072, K=1024
// 128x128 tile, BK=32, 4 waves (2x2), per-wave 64x64 = 4x4 fragments of 16x16x32.
// Epilogue scatters to q,k [B,H,T,D] bf16 and v^T [B,H,D,T] bf16.
__device__ __forceinline__ void stage_tile(const short* gbase, short* lbase, int tid) {
#pragma unroll
    for (int c = 0; c < 2; ++c) {
        int row = c * 64 + (tid >> 2);
        int chunk = tid & 3;
        const short* gp = gbase + (size_t)row * KDIM + chunk * 8;
        short* lp = lbase + c * 2048 + tid * 8;   // bytes: c*4096 + tid*16
        __builtin_amdgcn_global_load_lds((const __attribute__((address_space(1))) void*)gp,
                                         (__attribute__((address_space(3))) void*)lp,
                                         16, 0, 0);
    }
}

__global__ __launch_bounds__(256) void qkv_gemm_kernel(const short* __restrict__ xb,
                                                       const short* __restrict__ wt,
                                                       short* __restrict__ qb,
                                                       short* __restrict__ kbuf,
                                                       short* __restrict__ vt) {
    __shared__ short lA[2][128 * 32];
    __shared__ short lB[2][128 * 32];

    const int tid  = threadIdx.x;
    const int lane = tid & 63;
    const int wid  = tid >> 6;
    const int wm = wid >> 1, wn = wid & 1;
    const int m0 = blockIdx.y * 128;
    const int n0 = blockIdx.x * 128;

    f32x4 acc[4][4];
#pragma unroll
    for (int i = 0; i < 4; ++i)
#pragma unroll
        for (int j = 0; j < 4; ++j) acc[i][j] = (f32x4){0.f, 0.f, 0.f, 0.f};

    const short* gA = xb + (size_t)m0 * KDIM;
    const short* gB = wt + (size_t)n0 * KDIM;

    stage_tile(gA, lA[0], tid);
    stage_tile(gB, lB[0], tid);
    asm volatile("s_waitcnt vmcnt(0)" ::: "memory");
    __syncthreads();

    int cur = 0;
    const int arow = (lane & 15) * 32 + (lane >> 4) * 8;
#pragma unroll 1
    for (int kt = 0; kt < KDIM / 32; ++kt) {
        if (kt + 1 < KDIM / 32) {
            stage_tile(gA + (kt + 1) * 32, lA[cur ^ 1], tid);
            stage_tile(gB + (kt + 1) * 32, lB[cur ^ 1], tid);
        }
        short8 a[4], b[4];
#pragma unroll
        for (int im = 0; im < 4; ++im)
            a[im] = *(const short8*)&lA[cur][(wm * 64 + im * 16) * 32 + arow];
#pragma unroll
        for (int in = 0; in < 4; ++in)
            b[in] = *(const short8*)&lB[cur][(wn * 64 + in * 16) * 32 + arow];
#pragma unroll
        for (int im = 0; im < 4; ++im)
#pragma unroll
            for (int in = 0; in < 4; ++in)
                acc[im][in] = __builtin_amdgcn_mfma_f32_16x16x32_bf16(a[im], b[in], acc[im][in], 0, 0, 0);
        asm volatile("s_waitcnt vmcnt(0)" ::: "memory");
        __syncthreads();
        cur ^= 1;
    }

    // epilogue: scatter to q [B,H,T,D], k [B,H,T,D], v^T [B,H,D,T]
#pragma unroll
    for (int im = 0; im < 4; ++im) {
        int t0m = m0 + wm * 64 + im * 16 + (lane >> 4) * 4;
        int b = t0m >> 11;
        int t0 = t0m & 2047;
#pragma unroll
        for (int in = 0; in < 4; ++in) {
            int col = n0 + wn * 64 + in * 16 + (lane & 15);
            int which = col >> 10;
            int h = (col >> 6) & 15;
            int d = col & 63;
            if (which == 2) {
                u16x4 pk;
#pragma unroll
                for (int r = 0; r < 4; ++r) pk[r] = f2bf(acc[im][in][r]);
                *(u16x4*)&vt[((size_t)(b * NHEAD + h) * HDIM + d) * SEQ + t0] = pk;
            } else {
                short* dst = (which == 0) ? qb : kbuf;
#pragma unroll
                for (int r = 0; r < 4; ++r)
                    dst[((size_t)(b * NHEAD + h) * SEQ + t0 + r) * HDIM + d] = (short)f2bf(acc[im][in][r]);
            }
        }
    }
}

// ---------------------------------------------------------------- flash attention
// grid (SEQ/64, BATCH*NHEAD), 256 threads = 4 independent waves, 16 q-rows each.
__global__ __launch_bounds__(256) void attn_kernel(const short* __restrict__ q,
                                                   const short* __restrict__ kk,
                                                   const short* __restrict__ vtg,
                                                   float* __restrict__ out) {
    const int lane = threadIdx.x & 63;
    const int wid  = threadIdx.x >> 6;
    const int qt = blockIdx.x;
    const int bh = blockIdx.y;
    const int qbase = qt * 64 + wid * 16;

    const short* qh = q   + (size_t)bh * SEQ * HDIM;
    const short* kh = kk  + (size_t)bh * SEQ * HDIM;
    const short* vh = vtg + (size_t)bh * HDIM * SEQ;

    __shared__ short pshare[4][16 * 32];
    short* pw = pshare[wid];

    // Q fragments (A layout: m = lane&15, k = (lane>>4)*8 + j), k-chunks of 32
    short8 aQ[2];
#pragma unroll
    for (int c = 0; c < 2; ++c)
        aQ[c] = *(const short8*)&qh[(size_t)(qbase + (lane & 15)) * HDIM + c * 32 + (lane >> 4) * 8];

    f32x4 o[4];
#pragma unroll
    for (int i = 0; i < 4; ++i) o[i] = (f32x4){0.f, 0.f, 0.f, 0.f};
    float mrun[4] = {-INFINITY, -INFINITY, -INFINITY, -INFINITY};
    float lrun[4] = {0.f, 0.f, 0.f, 0.f};
    const float L2E = 1.4426950408889634f;

    for (int kb0 = 0; kb0 < qbase + 16; kb0 += 32) {
        // scores: 2 n-tiles of 16 keys
        f32x4 s[2];
#pragma unroll
        for (int nt = 0; nt < 2; ++nt) {
            f32x4 a = (f32x4){0.f, 0.f, 0.f, 0.f};
#pragma unroll
            for (int c = 0; c < 2; ++c) {
                short8 bK = *(const short8*)&kh[(size_t)(kb0 + nt * 16 + (lane & 15)) * HDIM + c * 32 + (lane >> 4) * 8];
                a = __builtin_amdgcn_mfma_f32_16x16x32_bf16(aQ[c], bK, a, 0, 0, 0);
            }
            int j = kb0 + nt * 16 + (lane & 15);
#pragma unroll
            for (int r = 0; r < 4; ++r) {
                int qrow = qbase + (lane >> 4) * 4 + r;
                s[nt][r] = (j <= qrow) ? a[r] * 0.125f : -1e30f;
            }
        }
        // online softmax (row groups = 16 lanes)
        float sf[4];
#pragma unroll
        for (int r = 0; r < 4; ++r) {
            float pm = fmaxf(s[0][r], s[1][r]);
#pragma unroll
            for (int msk = 1; msk < 16; msk <<= 1) pm = fmaxf(pm, __shfl_xor(pm, msk));
            float mnew = fmaxf(mrun[r], pm);
            sf[r] = exp2f((mrun[r] - mnew) * L2E);
            mrun[r] = mnew;
        }
        float ps[4] = {0.f, 0.f, 0.f, 0.f};
#pragma unroll
        for (int nt = 0; nt < 2; ++nt)
#pragma unroll
            for (int r = 0; r < 4; ++r) {
                float p = exp2f((s[nt][r] - mrun[r]) * L2E);
                s[nt][r] = p;
                ps[r] += p;
            }
#pragma unroll
        for (int r = 0; r < 4; ++r) {
#pragma unroll
            for (int msk = 1; msk < 16; msk <<= 1) ps[r] += __shfl_xor(ps[r], msk);
            lrun[r] = lrun[r] * sf[r] + ps[r];
        }
#pragma unroll
        for (int dt = 0; dt < 4; ++dt)
#pragma unroll
            for (int r = 0; r < 4; ++r) o[dt][r] *= sf[r];

        // P -> LDS (C layout) -> A-fragment layout
#pragma unroll
        for (int nt = 0; nt < 2; ++nt)
#pragma unroll
            for (int r = 0; r < 4; ++r)
                pw[((lane >> 4) * 4 + r) * 32 + nt * 16 + (lane & 15)] = (short)f2bf(s[nt][r]);
        asm volatile("s_waitcnt lgkmcnt(0)" ::: "memory");
        short8 pa = *(const short8*)&pw[(lane & 15) * 32 + (lane >> 4) * 8];

        // PV: O[q][d] += P[16x32] * V[32 x 64]
#pragma unroll
        for (int dt = 0; dt < 4; ++dt) {
            short8 bV = *(const short8*)&vh[(size_t)(dt * 16 + (lane & 15)) * SEQ + kb0 + (lane >> 4) * 8];
            o[dt] = __builtin_amdgcn_mfma_f32_16x16x32_bf16(pa, bV, o[dt], 0, 0, 0);
        }
    }

    // write out [B,T,H,D] fp32
    const int b = bh >> 4, h = bh & 15;
#pragma unroll
    for (int dt = 0; dt < 4; ++dt)
#pragma unroll
        for (int r = 0; r < 4; ++r) {
            int t = qbase + (lane >> 4) * 4 + r;
            out[((size_t)(b * SEQ + t) * NHEAD + h) * HDIM + dt * 16 + (lane & 15)] = o[dt][r] / lrun[r];
        }
}

// ---------------------------------------------------------------- launch
extern "C" void kernel_launch(void* const* d_in, const int* in_sizes, int n_in,
                              void* d_out, int out_size, void* d_ws, size_t ws_size,
                              hipStream_t stream) {
    const float* x = (const float*)d_in[0];
    const float* w = (const float*)d_in[1];
    float* out = (float*)d_out;

    char* ws = (char*)d_ws;
    short* xb   = (short*)(ws);                          // 8 MB  [M,K] bf16
    short* wt   = (short*)(ws + (size_t)8  * 1024 * 1024); // 6 MB  [N3,K] bf16
    short* qb   = (short*)(ws + (size_t)14 * 1024 * 1024); // 8 MB  [B,H,T,D]
    short* kbuf = (short*)(ws + (size_t)22 * 1024 * 1024); // 8 MB  [B,H,T,D]
    short* vt   = (short*)(ws + (size_t)30 * 1024 * 1024); // 8 MB  [B,H,D,T]

    cast_x_kernel<<<dim3(MTOT * KDIM / 4 / 256), dim3(256), 0, stream>>>(x, xb, MTOT * KDIM / 4);
    cast_wt_kernel<<<dim3(N3 / 32, KDIM / 32), dim3(256), 0, stream>>>(w, wt);
    qkv_gemm_kernel<<<dim3(N3 / 128, MTOT / 128), dim3(256), 0, stream>>>(xb, wt, qb, kbuf, vt);
    attn_kernel<<<dim3(SEQ / 64, BATCH * NHEAD), dim3(256), 0, stream>>>(qb, kbuf, vt, out);
}

// Round 2
// 190.297 us; speedup vs baseline: 1.4426x; 1.4426x over previous
//
#include <hip/hip_runtime.h>
#include <hip/hip_bf16.h>

// Problem constants
#define BATCH 2
#define SEQ   2048
#define EMBD  1024
#define NHEAD 16
#define HDIM  64
#define N3    3072           // 3*EMBD
#define MTOT  4096           // BATCH*SEQ
#define KDIM  1024

typedef __attribute__((ext_vector_type(8))) short  short8;   // 8 x bf16 (4 VGPRs)
typedef __attribute__((ext_vector_type(4))) short  s16x4;
typedef __attribute__((ext_vector_type(4))) unsigned short u16x4;
typedef __attribute__((ext_vector_type(4))) float  f32x4;

__device__ __forceinline__ unsigned short f2bf(float f) {
    unsigned int u = __builtin_bit_cast(unsigned int, f);
    u += 0x7fffu + ((u >> 16) & 1u);          // RNE
    return (unsigned short)(u >> 16);
}

// ---------------------------------------------------------------- cast x -> bf16
__global__ __launch_bounds__(256) void cast_x_kernel(const float* __restrict__ x,
                                                     short* __restrict__ xb, int n4) {
    int i = blockIdx.x * 256 + threadIdx.x;
    if (i >= n4) return;
    float4 f = reinterpret_cast<const float4*>(x)[i];
    s16x4 o;
    o[0] = (short)f2bf(f.x); o[1] = (short)f2bf(f.y);
    o[2] = (short)f2bf(f.z); o[3] = (short)f2bf(f.w);
    reinterpret_cast<s16x4*>(xb)[i] = o;
}

// ------------------------------------------- cast + transpose w [K,N3] -> wt [N3,K]
__global__ __launch_bounds__(256) void cast_wt_kernel(const float* __restrict__ w,
                                                      short* __restrict__ wt) {
    __shared__ float tile[32][33];
    int n0 = blockIdx.x * 32;   // N3/32 = 96
    int k0 = blockIdx.y * 32;   // K/32  = 32
    int tx = threadIdx.x & 31;
    int ty = threadIdx.x >> 5;  // 0..7
#pragma unroll
    for (int i = 0; i < 4; ++i)
        tile[ty + i * 8][tx] = w[(size_t)(k0 + ty + i * 8) * N3 + n0 + tx];
    __syncthreads();
#pragma unroll
    for (int i = 0; i < 4; ++i)
        wt[(size_t)(n0 + ty + i * 8) * KDIM + k0 + tx] = (short)f2bf(tile[tx][ty + i * 8]);
}

// ---------------------------------------------------------------- QKV GEMM
// C[m,n] = sum_k xb[m,k] * wt[n,k];  M=4096, N=3072, K=1024
__device__ __forceinline__ void stage_tile(const short* gbase, short* lbase, int tid) {
#pragma unroll
    for (int c = 0; c < 2; ++c) {
        int row = c * 64 + (tid >> 2);
        int chunk = tid & 3;
        const short* gp = gbase + (size_t)row * KDIM + chunk * 8;
        short* lp = lbase + c * 2048 + tid * 8;   // bytes: c*4096 + tid*16
        __builtin_amdgcn_global_load_lds((const __attribute__((address_space(1))) void*)gp,
                                         (__attribute__((address_space(3))) void*)lp,
                                         16, 0, 0);
    }
}

__global__ __launch_bounds__(256) void qkv_gemm_kernel(const short* __restrict__ xb,
                                                       const short* __restrict__ wt,
                                                       short* __restrict__ qb,
                                                       short* __restrict__ kbuf,
                                                       short* __restrict__ vt) {
    __shared__ short lA[2][128 * 32];
    __shared__ short lB[2][128 * 32];

    const int tid  = threadIdx.x;
    const int lane = tid & 63;
    const int wid  = tid >> 6;
    const int wm = wid >> 1, wn = wid & 1;
    const int m0 = blockIdx.y * 128;
    const int n0 = blockIdx.x * 128;

    f32x4 acc[4][4];
#pragma unroll
    for (int i = 0; i < 4; ++i)
#pragma unroll
        for (int j = 0; j < 4; ++j) acc[i][j] = (f32x4){0.f, 0.f, 0.f, 0.f};

    const short* gA = xb + (size_t)m0 * KDIM;
    const short* gB = wt + (size_t)n0 * KDIM;

    stage_tile(gA, lA[0], tid);
    stage_tile(gB, lB[0], tid);
    asm volatile("s_waitcnt vmcnt(0)" ::: "memory");
    __syncthreads();

    int cur = 0;
    const int arow = (lane & 15) * 32 + (lane >> 4) * 8;
#pragma unroll 1
    for (int kt = 0; kt < KDIM / 32; ++kt) {
        if (kt + 1 < KDIM / 32) {
            stage_tile(gA + (kt + 1) * 32, lA[cur ^ 1], tid);
            stage_tile(gB + (kt + 1) * 32, lB[cur ^ 1], tid);
        }
        short8 a[4], b[4];
#pragma unroll
        for (int im = 0; im < 4; ++im)
            a[im] = *(const short8*)&lA[cur][(wm * 64 + im * 16) * 32 + arow];
#pragma unroll
        for (int in = 0; in < 4; ++in)
            b[in] = *(const short8*)&lB[cur][(wn * 64 + in * 16) * 32 + arow];
#pragma unroll
        for (int im = 0; im < 4; ++im)
#pragma unroll
            for (int in = 0; in < 4; ++in)
                acc[im][in] = __builtin_amdgcn_mfma_f32_16x16x32_bf16(a[im], b[in], acc[im][in], 0, 0, 0);
        asm volatile("s_waitcnt vmcnt(0)" ::: "memory");
        __syncthreads();
        cur ^= 1;
    }

    // epilogue: scatter to q [B,H,T,D], k [B,H,T,D], v^T [B,H,D,T]
#pragma unroll
    for (int im = 0; im < 4; ++im) {
        int t0m = m0 + wm * 64 + im * 16 + (lane >> 4) * 4;
        int b = t0m >> 11;
        int t0 = t0m & 2047;
#pragma unroll
        for (int in = 0; in < 4; ++in) {
            int col = n0 + wn * 64 + in * 16 + (lane & 15);
            int which = col >> 10;
            int h = (col >> 6) & 15;
            int d = col & 63;
            if (which == 2) {
                u16x4 pk;
#pragma unroll
                for (int r = 0; r < 4; ++r) pk[r] = f2bf(acc[im][in][r]);
                *(u16x4*)&vt[((size_t)(b * NHEAD + h) * HDIM + d) * SEQ + t0] = pk;
            } else {
                short* dst = (which == 0) ? qb : kbuf;
#pragma unroll
                for (int r = 0; r < 4; ++r)
                    dst[((size_t)(b * NHEAD + h) * SEQ + t0 + r) * HDIM + d] = (short)f2bf(acc[im][in][r]);
            }
        }
    }
}

// ---------------------------------------------------------------- flash attention
// grid (SEQ/64, BATCH*NHEAD), 256 threads = 4 waves, 16 q-rows each (64 rows/block).
// K/V staged cooperatively in double-buffered LDS (KVBLK=64), XOR-swizzled:
// LDS dest linear (global_load_lds requirement), global SOURCE pre-swizzled,
// ds_read applies the same XOR (rule #21 both-sides-or-neither).
#define KVB 64

__device__ __forceinline__ void stage_kv(const short* kh, const short* vh, int kb,
                                         short* lk, short* lv, int tid) {
#pragma unroll
    for (int c = 0; c < 2; ++c) {
        int row = c * 32 + (tid >> 3);               // 0..63
        int sch = (tid & 7) ^ (row & 7);             // swizzled 16B-chunk index
        const short* gk = kh + (size_t)(kb + row) * HDIM + sch * 8;
        short* lpk = lk + c * 2048 + tid * 8;        // linear: byte = c*4096 + tid*16
        __builtin_amdgcn_global_load_lds((const __attribute__((address_space(1))) void*)gk,
                                         (__attribute__((address_space(3))) void*)lpk, 16, 0, 0);
        const short* gv = vh + (size_t)row * SEQ + kb + sch * 8;   // row = d index
        short* lpv = lv + c * 2048 + tid * 8;
        __builtin_amdgcn_global_load_lds((const __attribute__((address_space(1))) void*)gv,
                                         (__attribute__((address_space(3))) void*)lpv, 16, 0, 0);
    }
}

__global__ __launch_bounds__(256) void attn_kernel(const short* __restrict__ q,
                                                   const short* __restrict__ kk,
                                                   const short* __restrict__ vtg,
                                                   float* __restrict__ out) {
    const int tid  = threadIdx.x;
    const int lane = tid & 63;
    const int wid  = tid >> 6;
    const int qt = gridDim.x - 1 - blockIdx.x;       // longest blocks first
    const int bh = blockIdx.y;
    const int qbase = qt * 64 + wid * 16;
    const int rbase = lane & 15;
    const int hi    = lane >> 4;

    const short* qh = q   + (size_t)bh * SEQ * HDIM;
    const short* kh = kk  + (size_t)bh * SEQ * HDIM;
    const short* vh = vtg + (size_t)bh * HDIM * SEQ;

    __shared__ short lK[2][KVB * 64];
    __shared__ short lV[2][KVB * 64];
    __shared__ short psh[4][16 * 64];
    short* pw = psh[wid];

    // Q fragments (A layout: m = lane&15, k = hi*8 + j), two 32-wide k-chunks
    short8 aQ[2];
#pragma unroll
    for (int c = 0; c < 2; ++c)
        aQ[c] = *(const short8*)&qh[(size_t)(qbase + rbase) * HDIM + c * 32 + hi * 8];

    f32x4 o[4];
#pragma unroll
    for (int i = 0; i < 4; ++i) o[i] = (f32x4){0.f, 0.f, 0.f, 0.f};
    float mrun[4] = {-INFINITY, -INFINITY, -INFINITY, -INFINITY};
    float lrun[4] = {0.f, 0.f, 0.f, 0.f};
    const float L2E = 1.4426950408889634f;

    const int ntiles = qt + 1;
    stage_kv(kh, vh, 0, lK[0], lV[0], tid);
    asm volatile("s_waitcnt vmcnt(0)" ::: "memory");
    __syncthreads();

    int cur = 0;
#pragma unroll 1
    for (int t = 0; t < ntiles; ++t) {
        const int kb = t * KVB;
        if (t + 1 < ntiles)
            stage_kv(kh, vh, kb + KVB, lK[cur ^ 1], lV[cur ^ 1], tid);

        if (kb < qbase + 16) {   // wave-uniform: tile not fully masked for this wave
            const short* lk = lK[cur];
            const short* lv = lV[cur];
            // ---- QK^T: 4 n-tiles x 2 k-chunks
            f32x4 s[4];
#pragma unroll
            for (int nt = 0; nt < 4; ++nt) {
                int r = nt * 16 + rbase;
                f32x4 a = (f32x4){0.f, 0.f, 0.f, 0.f};
#pragma unroll
                for (int c = 0; c < 2; ++c) {
                    int cc = c * 4 + hi;
                    short8 bK = *(const short8*)&lk[r * 64 + ((cc ^ (r & 7)) * 8)];
                    a = __builtin_amdgcn_mfma_f32_16x16x32_bf16(aQ[c], bK, a, 0, 0, 0);
                }
                s[nt] = a;
            }
            // ---- mask + scale (mask only on the diagonal tile; wave-uniform branch)
            if (kb + KVB - 1 > qbase) {
#pragma unroll
                for (int nt = 0; nt < 4; ++nt) {
                    int j = kb + nt * 16 + rbase;
#pragma unroll
                    for (int r4 = 0; r4 < 4; ++r4) {
                        int qrow = qbase + hi * 4 + r4;
                        s[nt][r4] = (j <= qrow) ? s[nt][r4] * 0.125f : -1e30f;
                    }
                }
            } else {
#pragma unroll
                for (int nt = 0; nt < 4; ++nt)
#pragma unroll
                    for (int r4 = 0; r4 < 4; ++r4) s[nt][r4] *= 0.125f;
            }
            // ---- online softmax (16-lane groups hold one q-row's 16 keys)
            float sf[4];
#pragma unroll
            for (int r4 = 0; r4 < 4; ++r4) {
                float pm = fmaxf(fmaxf(s[0][r4], s[1][r4]), fmaxf(s[2][r4], s[3][r4]));
#pragma unroll
                for (int m = 1; m < 16; m <<= 1) pm = fmaxf(pm, __shfl_xor(pm, m));
                float mnew = fmaxf(mrun[r4], pm);
                sf[r4] = exp2f((mrun[r4] - mnew) * L2E);
                mrun[r4] = mnew;
            }
            float ps[4] = {0.f, 0.f, 0.f, 0.f};
#pragma unroll
            for (int nt = 0; nt < 4; ++nt)
#pragma unroll
                for (int r4 = 0; r4 < 4; ++r4) {
                    float p = exp2f((s[nt][r4] - mrun[r4]) * L2E);
                    s[nt][r4] = p;
                    ps[r4] += p;
                }
#pragma unroll
            for (int r4 = 0; r4 < 4; ++r4) {
#pragma unroll
                for (int m = 1; m < 16; m <<= 1) ps[r4] += __shfl_xor(ps[r4], m);
                lrun[r4] = lrun[r4] * sf[r4] + ps[r4];
            }
#pragma unroll
            for (int dt = 0; dt < 4; ++dt)
#pragma unroll
                for (int r4 = 0; r4 < 4; ++r4) o[dt][r4] *= sf[r4];

            // ---- P -> LDS (C layout, short-granular XOR swizzle) -> A fragments
#pragma unroll
            for (int nt = 0; nt < 4; ++nt)
#pragma unroll
                for (int r4 = 0; r4 < 4; ++r4) {
                    int prow = hi * 4 + r4;
                    int pcol = nt * 16 + rbase;
                    pw[prow * 64 + (pcol ^ ((prow & 7) << 3))] = (short)f2bf(s[nt][r4]);
                }
            asm volatile("s_waitcnt lgkmcnt(0)" ::: "memory");
            __builtin_amdgcn_sched_barrier(0);
            short8 pa[2];
#pragma unroll
            for (int ks = 0; ks < 2; ++ks) {
                int cc = ks * 4 + hi;
                pa[ks] = *(const short8*)&pw[rbase * 64 + ((cc ^ (rbase & 7)) * 8)];
            }
            // ---- PV: O[16 x 64] += P[16 x 64] * V[64 x 64]
#pragma unroll
            for (int dt = 0; dt < 4; ++dt) {
                int d = dt * 16 + rbase;
#pragma unroll
                for (int ks = 0; ks < 2; ++ks) {
                    int cc = ks * 4 + hi;
                    short8 bV = *(const short8*)&lv[d * 64 + ((cc ^ (d & 7)) * 8)];
                    o[dt] = __builtin_amdgcn_mfma_f32_16x16x32_bf16(pa[ks], bV, o[dt], 0, 0, 0);
                }
            }
        }
        asm volatile("s_waitcnt vmcnt(0)" ::: "memory");
        __syncthreads();
        cur ^= 1;
    }

    // write out [B,T,H,D] fp32
    const int b = bh >> 4, h = bh & 15;
#pragma unroll
    for (int dt = 0; dt < 4; ++dt)
#pragma unroll
        for (int r4 = 0; r4 < 4; ++r4) {
            int t = qbase + hi * 4 + r4;
            out[((size_t)(b * SEQ + t) * NHEAD + h) * HDIM + dt * 16 + rbase] = o[dt][r4] / lrun[r4];
        }
}

// ---------------------------------------------------------------- launch
extern "C" void kernel_launch(void* const* d_in, const int* in_sizes, int n_in,
                              void* d_out, int out_size, void* d_ws, size_t ws_size,
                              hipStream_t stream) {
    const float* x = (const float*)d_in[0];
    const float* w = (const float*)d_in[1];
    float* out = (float*)d_out;

    char* ws = (char*)d_ws;
    short* xb   = (short*)(ws);                            // 8 MB  [M,K] bf16
    short* wt   = (short*)(ws + (size_t)8  * 1024 * 1024); // 6 MB  [N3,K] bf16
    short* qb   = (short*)(ws + (size_t)14 * 1024 * 1024); // 8 MB  [B,H,T,D]
    short* kbuf = (short*)(ws + (size_t)22 * 1024 * 1024); // 8 MB  [B,H,T,D]
    short* vt   = (short*)(ws + (size_t)30 * 1024 * 1024); // 8 MB  [B,H,D,T]

    cast_x_kernel<<<dim3(MTOT * KDIM / 4 / 256), dim3(256), 0, stream>>>(x, xb, MTOT * KDIM / 4);
    cast_wt_kernel<<<dim3(N3 / 32, KDIM / 32), dim3(256), 0, stream>>>(w, wt);
    qkv_gemm_kernel<<<dim3(N3 / 128, MTOT / 128), dim3(256), 0, stream>>>(xb, wt, qb, kbuf, vt);
    attn_kernel<<<dim3(SEQ / 64, BATCH * NHEAD), dim3(256), 0, stream>>>(qb, kbuf, vt, out);
}

// Round 3
// 123.513 us; speedup vs baseline: 2.2226x; 1.5407x over previous
//
#include <hip/hip_runtime.h>
#include <hip/hip_bf16.h>

// Problem constants
#define BATCH 2
#define SEQ   2048
#define EMBD  1024
#define NHEAD 16
#define HDIM  64
#define N3    3072           // 3*EMBD
#define MTOT  4096           // BATCH*SEQ
#define KDIM  1024

typedef __attribute__((ext_vector_type(8))) short  short8;   // 8 x bf16 (4 VGPRs)
typedef __attribute__((ext_vector_type(4))) short  s16x4;
typedef __attribute__((ext_vector_type(4))) unsigned short u16x4;
typedef __attribute__((ext_vector_type(4))) float  f32x4;

__device__ __forceinline__ unsigned short f2bf(float f) {
    unsigned int u = __builtin_bit_cast(unsigned int, f);
    u += 0x7fffu + ((u >> 16) & 1u);          // RNE
    return (unsigned short)(u >> 16);
}

// ---------------------------------------------------------------- cast x -> bf16
__global__ __launch_bounds__(256) void cast_x_kernel(const float* __restrict__ x,
                                                     short* __restrict__ xb, int n4) {
    int i = blockIdx.x * 256 + threadIdx.x;
    if (i >= n4) return;
    float4 f = reinterpret_cast<const float4*>(x)[i];
    s16x4 o;
    o[0] = (short)f2bf(f.x); o[1] = (short)f2bf(f.y);
    o[2] = (short)f2bf(f.z); o[3] = (short)f2bf(f.w);
    reinterpret_cast<s16x4*>(xb)[i] = o;
}

// ------------------------------------------- cast + transpose w [K,N3] -> wt [N3,K]
__global__ __launch_bounds__(256) void cast_wt_kernel(const float* __restrict__ w,
                                                      short* __restrict__ wt) {
    __shared__ float tile[32][33];
    int n0 = blockIdx.x * 32;   // N3/32 = 96
    int k0 = blockIdx.y * 32;   // K/32  = 32
    int tx = threadIdx.x & 31;
    int ty = threadIdx.x >> 5;  // 0..7
#pragma unroll
    for (int i = 0; i < 4; ++i)
        tile[ty + i * 8][tx] = w[(size_t)(k0 + ty + i * 8) * N3 + n0 + tx];
    __syncthreads();
#pragma unroll
    for (int i = 0; i < 4; ++i)
        wt[(size_t)(n0 + ty + i * 8) * KDIM + k0 + tx] = (short)f2bf(tile[tx][ty + i * 8]);
}

// ---------------------------------------------------------------- QKV GEMM
// C[m,n] = sum_k xb[m,k] * wt[n,k];  M=4096, N=3072, K=1024
__device__ __forceinline__ void stage_tile(const short* gbase, short* lbase, int tid) {
#pragma unroll
    for (int c = 0; c < 2; ++c) {
        int row = c * 64 + (tid >> 2);
        int chunk = tid & 3;
        const short* gp = gbase + (size_t)row * KDIM + chunk * 8;
        short* lp = lbase + c * 2048 + tid * 8;   // bytes: c*4096 + tid*16
        __builtin_amdgcn_global_load_lds((const __attribute__((address_space(1))) void*)gp,
                                         (__attribute__((address_space(3))) void*)lp,
                                         16, 0, 0);
    }
}

__global__ __launch_bounds__(256) void qkv_gemm_kernel(const short* __restrict__ xb,
                                                       const short* __restrict__ wt,
                                                       short* __restrict__ qb,
                                                       short* __restrict__ kbuf,
                                                       short* __restrict__ vt) {
    __shared__ short lA[2][128 * 32];
    __shared__ short lB[2][128 * 32];

    const int tid  = threadIdx.x;
    const int lane = tid & 63;
    const int wid  = tid >> 6;
    const int wm = wid >> 1, wn = wid & 1;
    const int m0 = blockIdx.y * 128;
    const int n0 = blockIdx.x * 128;

    f32x4 acc[4][4];
#pragma unroll
    for (int i = 0; i < 4; ++i)
#pragma unroll
        for (int j = 0; j < 4; ++j) acc[i][j] = (f32x4){0.f, 0.f, 0.f, 0.f};

    const short* gA = xb + (size_t)m0 * KDIM;
    const short* gB = wt + (size_t)n0 * KDIM;

    stage_tile(gA, lA[0], tid);
    stage_tile(gB, lB[0], tid);
    asm volatile("s_waitcnt vmcnt(0)" ::: "memory");
    __syncthreads();

    int cur = 0;
    const int arow = (lane & 15) * 32 + (lane >> 4) * 8;
#pragma unroll 1
    for (int kt = 0; kt < KDIM / 32; ++kt) {
        if (kt + 1 < KDIM / 32) {
            stage_tile(gA + (kt + 1) * 32, lA[cur ^ 1], tid);
            stage_tile(gB + (kt + 1) * 32, lB[cur ^ 1], tid);
        }
        short8 a[4], b[4];
#pragma unroll
        for (int im = 0; im < 4; ++im)
            a[im] = *(const short8*)&lA[cur][(wm * 64 + im * 16) * 32 + arow];
#pragma unroll
        for (int in = 0; in < 4; ++in)
            b[in] = *(const short8*)&lB[cur][(wn * 64 + in * 16) * 32 + arow];
#pragma unroll
        for (int im = 0; im < 4; ++im)
#pragma unroll
            for (int in = 0; in < 4; ++in)
                acc[im][in] = __builtin_amdgcn_mfma_f32_16x16x32_bf16(a[im], b[in], acc[im][in], 0, 0, 0);
        asm volatile("s_waitcnt vmcnt(0)" ::: "memory");
        __syncthreads();
        cur ^= 1;
    }

    // epilogue: scatter to q [B,H,T,D], k [B,H,T,D], v^T [B,H,D,T]
#pragma unroll
    for (int im = 0; im < 4; ++im) {
        int t0m = m0 + wm * 64 + im * 16 + (lane >> 4) * 4;
        int b = t0m >> 11;
        int t0 = t0m & 2047;
#pragma unroll
        for (int in = 0; in < 4; ++in) {
            int col = n0 + wn * 64 + in * 16 + (lane & 15);
            int which = col >> 10;
            int h = (col >> 6) & 15;
            int d = col & 63;
            if (which == 2) {
                u16x4 pk;
#pragma unroll
                for (int r = 0; r < 4; ++r) pk[r] = f2bf(acc[im][in][r]);
                *(u16x4*)&vt[((size_t)(b * NHEAD + h) * HDIM + d) * SEQ + t0] = pk;
            } else {
                short* dst = (which == 0) ? qb : kbuf;
#pragma unroll
                for (int r = 0; r < 4; ++r)
                    dst[((size_t)(b * NHEAD + h) * SEQ + t0 + r) * HDIM + d] = (short)f2bf(acc[im][in][r]);
            }
        }
    }
}

// ---------------------------------------------------------------- flash attention
// grid (16, B*H): block i handles q-tiles {31-i, i} sequentially (uniform 33
// kv-tile-iterations per block -> balanced causal work). 4 waves, 16 q-rows each.
// K/V double-buffered LDS, XOR-swizzled, counted vmcnt (never 0 mid-loop).
#define KVB 64

__device__ __forceinline__ void stage_kv(const short* kh, const short* vh, int kb,
                                         short* lk, short* lv, int tid) {
#pragma unroll
    for (int c = 0; c < 2; ++c) {
        int row = c * 32 + (tid >> 3);               // 0..63
        int sch = (tid & 7) ^ (row & 7);             // swizzled 16B-chunk index
        const short* gk = kh + (size_t)(kb + row) * HDIM + sch * 8;
        short* lpk = lk + c * 2048 + tid * 8;        // linear: byte = c*4096 + tid*16
        __builtin_amdgcn_global_load_lds((const __attribute__((address_space(1))) void*)gk,
                                         (__attribute__((address_space(3))) void*)lpk, 16, 0, 0);
        const short* gv = vh + (size_t)row * SEQ + kb + sch * 8;   // row = d index
        short* lpv = lv + c * 2048 + tid * 8;
        __builtin_amdgcn_global_load_lds((const __attribute__((address_space(1))) void*)gv,
                                         (__attribute__((address_space(3))) void*)lpv, 16, 0, 0);
    }
}

__global__ __launch_bounds__(256) void attn_kernel(const short* __restrict__ q,
                                                   const short* __restrict__ kk,
                                                   const short* __restrict__ vtg,
                                                   float* __restrict__ out) {
    const int tid  = threadIdx.x;
    const int lane = tid & 63;
    const int wid  = tid >> 6;
    const int pid = blockIdx.x;                      // 0..15
    const int bh = blockIdx.y;
    const int rbase = lane & 15;
    const int hi    = lane >> 4;

    const short* qh = q   + (size_t)bh * SEQ * HDIM;
    const short* kh = kk  + (size_t)bh * SEQ * HDIM;
    const short* vh = vtg + (size_t)bh * HDIM * SEQ;

    __shared__ short lK[2][KVB * 64];
    __shared__ short lV[2][KVB * 64];
    __shared__ short psh[4][16 * 64];
    short* pw = psh[wid];

    const float L2E = 1.4426950408889634f;
    const float C1  = 0.125f * 1.4426950408889634f;   // scale folded into exp2
    short8 vone;
#pragma unroll
    for (int j = 0; j < 8; ++j) vone[j] = (short)0x3F80;   // bf16 1.0

    const int b = bh >> 4, h = bh & 15;

#pragma unroll 1
    for (int seg = 0; seg < 2; ++seg) {
        const int qt = seg ? pid : (31 - pid);
        const int qbase = qt * 64 + wid * 16;

        // Q fragments (A layout: m = lane&15, k = hi*8 + j), two 32-wide k-chunks
        short8 aQ[2];
#pragma unroll
        for (int c = 0; c < 2; ++c)
            aQ[c] = *(const short8*)&qh[(size_t)(qbase + rbase) * HDIM + c * 32 + hi * 8];

        f32x4 o[4];
#pragma unroll
        for (int i = 0; i < 4; ++i) o[i] = (f32x4){0.f, 0.f, 0.f, 0.f};
        float mrun[4] = {-INFINITY, -INFINITY, -INFINITY, -INFINITY};
        float lrun[4] = {0.f, 0.f, 0.f, 0.f};

        const int ktiles = qt + 1;
        stage_kv(kh, vh, 0, lK[0], lV[0], tid);
        int cur = 0;
#pragma unroll 1
        for (int t = 0; t < ktiles; ++t) {
            const int kb = t * KVB;
            if (t + 1 < ktiles) {
                stage_kv(kh, vh, kb + KVB, lK[cur ^ 1], lV[cur ^ 1], tid);
                asm volatile("s_waitcnt vmcnt(4) lgkmcnt(0)" ::: "memory");
            } else {
                asm volatile("s_waitcnt vmcnt(0) lgkmcnt(0)" ::: "memory");
            }
            __builtin_amdgcn_s_barrier();
            __builtin_amdgcn_sched_barrier(0);

            if (kb < qbase + 16) {   // wave-uniform: tile not fully masked for this wave
                const short* lk = lK[cur];
                const short* lv = lV[cur];
                // ---- QK^T: 4 n-tiles x 2 k-chunks (raw scores, scale folded later)
                f32x4 s[4];
                __builtin_amdgcn_s_setprio(1);
#pragma unroll
                for (int nb = 0; nb < 4; ++nb) {
                    int r = nb * 16 + rbase;
                    f32x4 a = (f32x4){0.f, 0.f, 0.f, 0.f};
#pragma unroll
                    for (int c = 0; c < 2; ++c) {
                        int cc = c * 4 + hi;
                        short8 bK = *(const short8*)&lk[r * 64 + ((cc ^ (r & 7)) * 8)];
                        a = __builtin_amdgcn_mfma_f32_16x16x32_bf16(aQ[c], bK, a, 0, 0, 0);
                    }
                    s[nb] = a;
                }
                __builtin_amdgcn_s_setprio(0);
                // ---- causal mask (diagonal tile only; wave-uniform branch)
                if (kb + KVB - 1 > qbase) {
#pragma unroll
                    for (int nb = 0; nb < 4; ++nb) {
                        int j = kb + nb * 16 + rbase;
#pragma unroll
                        for (int r4 = 0; r4 < 4; ++r4) {
                            int qrow = qbase + hi * 4 + r4;
                            if (j > qrow) s[nb][r4] = -1e30f;
                        }
                    }
                }
                // ---- row max (16-lane groups hold one q-row's 16 keys)
                float pms[4];
                bool grow = false;
#pragma unroll
                for (int r4 = 0; r4 < 4; ++r4) {
                    float pm = fmaxf(fmaxf(s[0][r4], s[1][r4]), fmaxf(s[2][r4], s[3][r4]));
#pragma unroll
                    for (int m = 1; m < 16; m <<= 1) pm = fmaxf(pm, __shfl_xor(pm, m));
                    pms[r4] = pm * 0.125f;
                    grow = grow || (pms[r4] > mrun[r4]);
                }
                // ---- defer-max: rescale only when some row's max grew
                if (__any(grow)) {
#pragma unroll
                    for (int r4 = 0; r4 < 4; ++r4) {
                        float mnew = fmaxf(mrun[r4], pms[r4]);
                        float sf = exp2f((mrun[r4] - mnew) * L2E);
                        mrun[r4] = mnew;
                        lrun[r4] *= sf;
#pragma unroll
                        for (int dt = 0; dt < 4; ++dt) o[dt][r4] *= sf;
                    }
                }
                float mterm[4];
#pragma unroll
                for (int r4 = 0; r4 < 4; ++r4) mterm[r4] = mrun[r4] * L2E;

                // ---- P = exp2(s*C1 - mterm) -> bf16 -> LDS (swizzled)
#pragma unroll
                for (int nb = 0; nb < 4; ++nb)
#pragma unroll
                    for (int r4 = 0; r4 < 4; ++r4) {
                        float p = exp2f(fmaf(s[nb][r4], C1, -mterm[r4]));
                        int prow = hi * 4 + r4;
                        int pcol = nb * 16 + rbase;
                        pw[prow * 64 + (pcol ^ ((prow & 7) << 3))] =
                            __builtin_bit_cast(short, __float2bfloat16(p));
                    }
                asm volatile("s_waitcnt lgkmcnt(0)" ::: "memory");
                __builtin_amdgcn_sched_barrier(0);
                short8 pa[2];
#pragma unroll
                for (int ks = 0; ks < 2; ++ks) {
                    int cc = ks * 4 + hi;
                    pa[ks] = *(const short8*)&pw[rbase * 64 + ((cc ^ (rbase & 7)) * 8)];
                }
                // ---- PV + row-sum via ones-column MFMA
                f32x4 osum = (f32x4){0.f, 0.f, 0.f, 0.f};
                __builtin_amdgcn_s_setprio(1);
#pragma unroll
                for (int dt = 0; dt < 4; ++dt) {
                    int d = dt * 16 + rbase;
#pragma unroll
                    for (int ks = 0; ks < 2; ++ks) {
                        int cc = ks * 4 + hi;
                        short8 bV = *(const short8*)&lv[d * 64 + ((cc ^ (d & 7)) * 8)];
                        o[dt] = __builtin_amdgcn_mfma_f32_16x16x32_bf16(pa[ks], bV, o[dt], 0, 0, 0);
                    }
                }
#pragma unroll
                for (int ks = 0; ks < 2; ++ks)
                    osum = __builtin_amdgcn_mfma_f32_16x16x32_bf16(pa[ks], vone, osum, 0, 0, 0);
                __builtin_amdgcn_s_setprio(0);
#pragma unroll
                for (int r4 = 0; r4 < 4; ++r4) lrun[r4] += osum[r4];
            }
            __builtin_amdgcn_sched_barrier(0);
            __builtin_amdgcn_s_barrier();
            cur ^= 1;
        }

        // write out [B,T,H,D] fp32
#pragma unroll
        for (int r4 = 0; r4 < 4; ++r4) {
            float inv = 1.0f / lrun[r4];
            int tq = qbase + hi * 4 + r4;
#pragma unroll
            for (int dt = 0; dt < 4; ++dt)
                out[((size_t)(b * SEQ + tq) * NHEAD + h) * HDIM + dt * 16 + rbase] = o[dt][r4] * inv;
        }
    }
}

// ---------------------------------------------------------------- launch
extern "C" void kernel_launch(void* const* d_in, const int* in_sizes, int n_in,
                              void* d_out, int out_size, void* d_ws, size_t ws_size,
                              hipStream_t stream) {
    const float* x = (const float*)d_in[0];
    const float* w = (const float*)d_in[1];
    float* out = (float*)d_out;

    char* ws = (char*)d_ws;
    short* xb   = (short*)(ws);                            // 8 MB  [M,K] bf16
    short* wt   = (short*)(ws + (size_t)8  * 1024 * 1024); // 6 MB  [N3,K] bf16
    short* qb   = (short*)(ws + (size_t)14 * 1024 * 1024); // 8 MB  [B,H,T,D]
    short* kbuf = (short*)(ws + (size_t)22 * 1024 * 1024); // 8 MB  [B,H,T,D]
    short* vt   = (short*)(ws + (size_t)30 * 1024 * 1024); // 8 MB  [B,H,D,T]

    cast_x_kernel<<<dim3(MTOT * KDIM / 4 / 256), dim3(256), 0, stream>>>(x, xb, MTOT * KDIM / 4);
    cast_wt_kernel<<<dim3(N3 / 32, KDIM / 32), dim3(256), 0, stream>>>(w, wt);
    qkv_gemm_kernel<<<dim3(N3 / 128, MTOT / 128), dim3(256), 0, stream>>>(xb, wt, qb, kbuf, vt);
    attn_kernel<<<dim3(16, BATCH * NHEAD), dim3(256), 0, stream>>>(qb, kbuf, vt, out);
}